// Round 5
// baseline (903.885 us; speedup 1.0000x reference)
//
#include <hip/hip_runtime.h>

#define CH 128
#define NPB 16    // nodes per block in k_edge
#define MAXT 96   // tile descriptors per chunk

typedef _Float16 f16;
typedef _Float16 f16x8 __attribute__((ext_vector_type(8)));
typedef float f32x4 __attribute__((ext_vector_type(4)));

__device__ __forceinline__ f32x4 mfma16(f16x8 a, f16x8 b, f32x4 c) {
    return __builtin_amdgcn_mfma_f32_16x16x32_f16(a, b, c, 0, 0, 0);
}

// ---------------- fused front: hist + weight prep (3 layers) + x->f16 cvt ----------------
__global__ __launch_bounds__(256) void k_front(const int* __restrict__ edst, int* __restrict__ counts, int E,
                                               const float* __restrict__ W1a, const float* __restrict__ W2a,
                                               const float* __restrict__ W1b, const float* __restrict__ W2b,
                                               const float* __restrict__ W1c, const float* __restrict__ W2c,
                                               f16* __restrict__ WcT, f16* __restrict__ W2T,
                                               const float* __restrict__ x, f16* __restrict__ act,
                                               int total4, int gHist) {
    int bid = blockIdx.x;
    if (bid < gHist) {
        int e = bid * 256 + threadIdx.x;
        if (e < E) atomicAdd(&counts[edst[e]], 1);
    } else if (bid < gHist + 576) {
        int r = bid - gHist;
        int l = r / 192;
        const float* W1 = (l == 0) ? W1a : (l == 1) ? W1b : W1c;
        const float* W2 = (l == 0) ? W2a : (l == 1) ? W2b : W2c;
        f16* wct = WcT + l * 256 * CH;
        f16* w2t = W2T + l * CH * CH;
        int id = (r % 192) * 256 + threadIdx.x;   // 49152 per layer
        if (id < 32768) {
            int n = id >> 7, k = id & 127;
            float v;
            if (n < CH) v = W1[k * CH + n] - W1[(CH + k) * CH + n];
            else        v = W1[(CH + k) * CH + (n - CH)];
            wct[n * CH + k] = (f16)v;
        } else {
            int rr = id - 32768;
            int n = rr >> 7, k = rr & 127;
            w2t[n * CH + k] = (f16)W2[k * CH + n];
        }
    } else {
        int i = (bid - gHist - 576) * 256 + threadIdx.x;
        if (i < total4) {
            float4 v = ((const float4*)x)[i];
            f16 h0 = (f16)v.x, h1 = (f16)v.y, h2 = (f16)v.z, h3 = (f16)v.w;
            short4 s;
            s.x = *(short*)&h0; s.y = *(short*)&h1; s.z = *(short*)&h2; s.w = *(short*)&h3;
            ((short4*)act)[i] = s;
        }
    }
}

// ---------------- CSR scans + scatter ----------------
__global__ __launch_bounds__(256) void k_scan1(const int* __restrict__ counts, int* __restrict__ row_ptr,
                                               int* __restrict__ blockSums, int n) {
    __shared__ int s[256];
    int t = threadIdx.x;
    int i = blockIdx.x * 256 + t;
    s[t] = (i < n) ? counts[i] : 0;
    __syncthreads();
    for (int off = 1; off < 256; off <<= 1) {
        int x = (t >= off) ? s[t - off] : 0;
        __syncthreads();
        s[t] += x;
        __syncthreads();
    }
    if (i < n) row_ptr[i + 1] = s[t];
    if (t == 255) blockSums[blockIdx.x] = s[255];
}

__global__ __launch_bounds__(256) void k_scan2(const int* __restrict__ blockSums, int* __restrict__ blockOff, int nb) {
    __shared__ int s[256];
    int t = threadIdx.x;
    s[t] = (t < nb) ? blockSums[t] : 0;
    __syncthreads();
    for (int off = 1; off < 256; off <<= 1) {
        int x = (t >= off) ? s[t - off] : 0;
        __syncthreads();
        s[t] += x;
        __syncthreads();
    }
    blockOff[t] = (t == 0) ? 0 : s[t - 1];
}

__global__ __launch_bounds__(256) void k_scan3(int* __restrict__ row_ptr, const int* __restrict__ blockOff, int n) {
    int i = blockIdx.x * 256 + threadIdx.x;
    if (i < n) row_ptr[i + 1] += blockOff[blockIdx.x];
    if (blockIdx.x == 0 && threadIdx.x == 0) row_ptr[0] = 0;
}

__global__ __launch_bounds__(256) void k_scatter(const int* __restrict__ src, const int* __restrict__ dst,
                                                 const int* __restrict__ row_ptr, int* __restrict__ cursor,
                                                 int* __restrict__ ssrc, int E) {
    int e = blockIdx.x * 256 + threadIdx.x;
    if (e < E) {
        int d = dst[e];
        int pos = row_ptr[d] + atomicAdd(&cursor[d], 1);
        ssrc[pos] = src[e];
    }
}

// ---------------- node GEMM: [P|Q] = act @ WcT^T, P gets +b1 ----------------
__global__ __launch_bounds__(256) void k_gemm1(const f16* __restrict__ act, const f16* __restrict__ WcT,
                                               const float* __restrict__ b1,
                                               f16* __restrict__ P, f16* __restrict__ Q, int nrows) {
    int t = threadIdx.x;
    int w = t >> 6, lane = t & 63;
    int m = lane & 15, q = lane >> 4;
    int row0 = blockIdx.x * 64 + w * 16;
    int rowc = min(row0 + m, nrows - 1);
    f16x8 a[4];
#pragma unroll
    for (int kk = 0; kk < 4; ++kk)
        a[kk] = *(const f16x8*)(act + rowc * CH + kk * 32 + q * 8);
#pragma unroll
    for (int nb = 0; nb < 16; ++nb) {
        f32x4 acc = {0.f, 0.f, 0.f, 0.f};
#pragma unroll
        for (int kk = 0; kk < 4; ++kk) {
            f16x8 b = *(const f16x8*)(WcT + (nb * 16 + m) * CH + kk * 32 + q * 8);
            acc = mfma16(a[kk], b, acc);
        }
        int col = nb * 16 + m;
        float bias = (nb < 8) ? b1[col] : 0.f;
#pragma unroll
        for (int r = 0; r < 4; ++r) {
            int ro = row0 + q * 4 + r;
            if (ro < nrows) {
                float v = acc[r] + bias;
                if (nb < 8) P[ro * CH + col] = (f16)v;
                else        Q[ro * CH + (col - CH)] = (f16)v;
            }
        }
    }
}

// ---------------- fused edge GEMM + segmented max ----------------
// 4-wave cooperative, dst-sorted CSR, 16-edge tiles (small LDS -> ~6 blocks/CU),
// descriptor-driven, packed relu, mov-free 2x-unrolled pipeline.
// flags: bit0 relu out, bit1 fp32 out.
__global__ __launch_bounds__(256, 6) void k_edge(const f16* __restrict__ P, const f16* __restrict__ Q,
                                                 const f16* __restrict__ W2Tg, const float* __restrict__ b2,
                                                 const int* __restrict__ row_ptr, const int* __restrict__ ssrc,
                                                 f16* __restrict__ act_out, float* __restrict__ final_out,
                                                 int n_nodes, int flags) {
    __shared__ f16 buf[2][16 * 136];
    __shared__ int rp[NPB + 1];
    __shared__ int tnd[MAXT], te0[MAXT];
    __shared__ int ntd_s, more_s;

    int t = threadIdx.x;
    int w = t >> 6, lane = t & 63;
    int m1 = lane & 15, q1 = lane >> 4;   // consumer coords
    int mp = t >> 4, c = t & 15;          // producer coords: edge-in-tile, chunk
    int n0 = blockIdx.x * NPB;

    if (t <= NPB) rp[t] = row_ptr[min(n0 + t, n_nodes)];

    // this wave's 2 nb-blocks of W2^T (32 VGPRs)
    f16x8 bf[2][4];
#pragma unroll
    for (int i2 = 0; i2 < 2; ++i2)
#pragma unroll
        for (int kk = 0; kk < 4; ++kk)
            bf[i2][kk] = *(const f16x8*)(W2Tg + ((2 * w + i2) * 16 + m1) * CH + kk * 32 + q1 * 8);
    float bias0 = b2[(2 * w) * 16 + m1];
    float bias1 = b2[(2 * w + 1) * 16 + m1];

    f32x4 mx[2];
    mx[0] = {-1e30f, -1e30f, -1e30f, -1e30f};
    mx[1] = {-1e30f, -1e30f, -1e30f, -1e30f};
    int cur_nd = -1;
    const f16x8 z8 = {};

    auto flush = [&](int nd) {
        if (nd >= 0) {
            int node = n0 + nd;
#pragma unroll
            for (int i2 = 0; i2 < 2; ++i2) {
                float v = fmaxf(fmaxf(mx[i2][0], mx[i2][1]), fmaxf(mx[i2][2], mx[i2][3]));
                v = fmaxf(v, __shfl_xor(v, 16));
                v = fmaxf(v, __shfl_xor(v, 32));
                if (q1 == 0) {
                    int col = (2 * w + i2) * 16 + m1;
                    float o = v + (i2 ? bias1 : bias0);
                    if (flags & 1) o = fmaxf(o, 0.f);
                    if (flags & 2) final_out[(size_t)node * CH + col] = o;
                    else           act_out[(size_t)node * CH + col] = (f16)o;
                }
                mx[i2] = {-1e30f, -1e30f, -1e30f, -1e30f};
            }
        }
    };

    int w_nd = 0, w_e = -2000000000;   // walker state (thread 0 only)

    for (;;) {
        __syncthreads();
        if (t == 0) {
            int k = 0;
            while (w_nd < NPB && k < MAXT) {
                int rs = rp[w_nd], re = rp[w_nd + 1];
                if (w_e < rs) w_e = rs;
                if (w_e < re) { tnd[k] = w_nd; te0[k] = w_e; ++k; w_e += 16; }
                else          { ++w_nd; w_e = -2000000000; }
            }
            ntd_s = k;
            more_s = (w_nd < NPB) ? 1 : 0;
        }
        __syncthreads();
        int ntd = ntd_s, more = more_s;

        if (ntd > 0) {
            f16x8 qD0, pD0, qD1, pD1;
            int s0 = 0, s1 = 0;
            // prologue: produce tile 0, load data for tile 1, s-idx for tile 2
            {
                int nd = tnd[0], e0 = te0[0], re = rp[nd + 1];
                int sA = ssrc[min(e0 + mp, re - 1)];
                f16x8 qa = *(const f16x8*)(Q + (size_t)sA * CH + c * 8);
                f16x8 pp = *(const f16x8*)(P + (size_t)(n0 + nd) * CH + c * 8);
                *(f16x8*)&buf[0][mp * 136 + c * 8] = __builtin_elementwise_max(pp + qa, z8);
            }
            if (ntd > 1) {
                int nd = tnd[1], e0 = te0[1], re = rp[nd + 1];
                int sA = ssrc[min(e0 + mp, re - 1)];
                qD1 = *(const f16x8*)(Q + (size_t)sA * CH + c * 8);
                pD1 = *(const f16x8*)(P + (size_t)(n0 + nd) * CH + c * 8);
            }
            if (ntd > 2) {
                int nd = tnd[2], e0 = te0[2], re = rp[nd + 1];
                s0 = ssrc[min(e0 + mp, re - 1)];
            }
            __syncthreads();

            auto step = [&](int i, int par,
                            f16x8& pq, f16x8& pP,     // data for tile i+1 (produce now)
                            f16x8& nq, f16x8& nP,     // fill: data for tile i+2
                            int sNow,                  // s-idx for tile i+2
                            int& sNext) {              // fill: s-idx for tile i+3
                if (i + 3 < ntd) {
                    int nd = tnd[i + 3], e0 = te0[i + 3], re = rp[nd + 1];
                    sNext = ssrc[min(e0 + mp, re - 1)];
                }
                if (i + 2 < ntd) {
                    int nd = tnd[i + 2];
                    nq = *(const f16x8*)(Q + (size_t)sNow * CH + c * 8);
                    nP = *(const f16x8*)(P + (size_t)(n0 + nd) * CH + c * 8);
                }
                int ndc = tnd[i];
                if (ndc != cur_nd) { flush(cur_nd); cur_nd = ndc; }
                {
                    const f16* bp = &buf[par][0];
                    f16x8 af[4];
#pragma unroll
                    for (int kk = 0; kk < 4; ++kk)
                        af[kk] = *(const f16x8*)&bp[m1 * 136 + kk * 32 + q1 * 8];
                    f32x4 a0 = {0.f, 0.f, 0.f, 0.f}, a1 = {0.f, 0.f, 0.f, 0.f};
#pragma unroll
                    for (int kk = 0; kk < 4; ++kk) {
                        a0 = mfma16(af[kk], bf[0][kk], a0);
                        a1 = mfma16(af[kk], bf[1][kk], a1);
                    }
                    mx[0] = __builtin_elementwise_max(mx[0], a0);
                    mx[1] = __builtin_elementwise_max(mx[1], a1);
                }
                if (i + 1 < ntd)
                    *(f16x8*)&buf[par ^ 1][mp * 136 + c * 8] = __builtin_elementwise_max(pP + pq, z8);
                __syncthreads();
            };

            int i = 0;
            while (i < ntd) {
                step(i, 0, qD1, pD1, qD0, pD0, s0, s1); ++i;
                if (i >= ntd) break;
                step(i, 1, qD0, pD0, qD1, pD1, s1, s0); ++i;
            }
        }
        if (!more) break;
    }
    flush(cur_nd);

    // zero-degree nodes
    for (int j = 0; j < NPB; ++j) {
        int node = n0 + j;
        if (node < n_nodes && rp[j + 1] == rp[j] && t < CH) {
            if (flags & 2) final_out[(size_t)node * CH + t] = 0.f;
            else           act_out[(size_t)node * CH + t] = (f16)0.f;
        }
    }
}

extern "C" void kernel_launch(void* const* d_in, const int* in_sizes, int n_in,
                              void* d_out, int out_size, void* d_ws, size_t ws_size,
                              hipStream_t stream) {
    const float* x = (const float*)d_in[0];
    const int* ei  = (const int*)d_in[1];
    int E = in_sizes[1] / 2;
    int N = in_sizes[0] / CH;
    const int* esrc = ei;
    const int* edst = ei + E;

    const float* W1[3] = {(const float*)d_in[2], (const float*)d_in[6],  (const float*)d_in[10]};
    const float* B1[3] = {(const float*)d_in[3], (const float*)d_in[7],  (const float*)d_in[11]};
    const float* W2[3] = {(const float*)d_in[4], (const float*)d_in[8],  (const float*)d_in[12]};
    const float* B2[3] = {(const float*)d_in[5], (const float*)d_in[9],  (const float*)d_in[13]};

    char* base = (char*)d_ws;
    size_t off = 0;
    auto alloc = [&](size_t bytes) -> void* {
        void* p = base + off;
        off = (off + bytes + 255) & ~(size_t)255;
        return p;
    };
    int* counts    = (int*)alloc(sizeof(int) * (size_t)(N + 256));
    int* cursor    = (int*)alloc(sizeof(int) * (size_t)(N + 256));
    size_t zero_bytes = off;                       // counts + cursor must start at 0
    int* row_ptr   = (int*)alloc(sizeof(int) * (size_t)(N + 1));
    int* blockSums = (int*)alloc(sizeof(int) * 256);
    int* blockOff  = (int*)alloc(sizeof(int) * 256);
    int* ssrc      = (int*)alloc(sizeof(int) * (size_t)E);
    f16* act       = (f16*)alloc(sizeof(f16) * (size_t)N * CH);
    f16* Pb        = (f16*)alloc(sizeof(f16) * (size_t)N * CH);
    f16* Qb        = (f16*)alloc(sizeof(f16) * (size_t)N * CH);
    f16* WcT       = (f16*)alloc(sizeof(f16) * 3 * 256 * CH);
    f16* W2T       = (f16*)alloc(sizeof(f16) * 3 * CH * CH);

    hipMemsetAsync(d_ws, 0, zero_bytes, stream);

    int gE = (E + 255) / 256;
    int gN = (N + 255) / 256;
    int total4 = N * CH / 4;
    int gCvt = (total4 + 255) / 256;
    // fused: hist + 3x prep + cvt
    k_front<<<gE + 576 + gCvt, 256, 0, stream>>>(edst, counts, E,
                                                 W1[0], W2[0], W1[1], W2[1], W1[2], W2[2],
                                                 WcT, W2T, x, act, total4, gE);
    k_scan1<<<gN, 256, 0, stream>>>(counts, row_ptr, blockSums, N);
    k_scan2<<<1, 256, 0, stream>>>(blockSums, blockOff, gN);
    k_scan3<<<gN, 256, 0, stream>>>(row_ptr, blockOff, N);
    k_scatter<<<gE, 256, 0, stream>>>(esrc, edst, row_ptr, cursor, ssrc, E);

    int gEdge = (N + NPB - 1) / NPB;
    for (int l = 0; l < 3; ++l) {
        k_gemm1<<<(N + 63) / 64, 256, 0, stream>>>(act, WcT + l * 256 * CH, B1[l], Pb, Qb, N);
        int flags = (l < 2 ? 1 : 0) | (l == 2 ? 2 : 0);
        k_edge<<<gEdge, 256, 0, stream>>>(Pb, Qb, W2T + l * CH * CH, B2[l],
                                          row_ptr, ssrc, act, (float*)d_out, N, flags);
    }
}

// Round 6
// 602.609 us; speedup vs baseline: 1.5000x; 1.5000x over previous
//
#include <hip/hip_runtime.h>

#define CH 128
#define NPB 16    // nodes per block in k_edge
#define MAXT 96   // tile descriptors per chunk

typedef _Float16 f16;
typedef _Float16 f16x8 __attribute__((ext_vector_type(8)));
typedef float f32x4 __attribute__((ext_vector_type(4)));

__device__ __forceinline__ f32x4 mfma16(f16x8 a, f16x8 b, f32x4 c) {
    return __builtin_amdgcn_mfma_f32_16x16x32_f16(a, b, c, 0, 0, 0);
}

// ---------------- fused front: hist + weight prep (3 layers) + x->f16 cvt ----------------
__global__ __launch_bounds__(256) void k_front(const int* __restrict__ edst, int* __restrict__ counts, int E,
                                               const float* __restrict__ W1a, const float* __restrict__ W2a,
                                               const float* __restrict__ W1b, const float* __restrict__ W2b,
                                               const float* __restrict__ W1c, const float* __restrict__ W2c,
                                               f16* __restrict__ WcT, f16* __restrict__ W2T,
                                               const float* __restrict__ x, f16* __restrict__ act,
                                               int total4, int gHist) {
    int bid = blockIdx.x;
    if (bid < gHist) {
        int e = bid * 256 + threadIdx.x;
        if (e < E) atomicAdd(&counts[edst[e]], 1);
    } else if (bid < gHist + 576) {
        int r = bid - gHist;
        int l = r / 192;
        const float* W1 = (l == 0) ? W1a : (l == 1) ? W1b : W1c;
        const float* W2 = (l == 0) ? W2a : (l == 1) ? W2b : W2c;
        f16* wct = WcT + l * 256 * CH;
        f16* w2t = W2T + l * CH * CH;
        int id = (r % 192) * 256 + threadIdx.x;   // 49152 per layer
        if (id < 32768) {
            int n = id >> 7, k = id & 127;
            float v;
            if (n < CH) v = W1[k * CH + n] - W1[(CH + k) * CH + n];
            else        v = W1[(CH + k) * CH + (n - CH)];
            wct[n * CH + k] = (f16)v;
        } else {
            int rr = id - 32768;
            int n = rr >> 7, k = rr & 127;
            w2t[n * CH + k] = (f16)W2[k * CH + n];
        }
    } else {
        int i = (bid - gHist - 576) * 256 + threadIdx.x;
        if (i < total4) {
            float4 v = ((const float4*)x)[i];
            f16 h0 = (f16)v.x, h1 = (f16)v.y, h2 = (f16)v.z, h3 = (f16)v.w;
            short4 s;
            s.x = *(short*)&h0; s.y = *(short*)&h1; s.z = *(short*)&h2; s.w = *(short*)&h3;
            ((short4*)act)[i] = s;
        }
    }
}

// ---------------- CSR scans + scatter ----------------
__global__ __launch_bounds__(256) void k_scan1(const int* __restrict__ counts, int* __restrict__ row_ptr,
                                               int* __restrict__ blockSums, int n) {
    __shared__ int s[256];
    int t = threadIdx.x;
    int i = blockIdx.x * 256 + t;
    s[t] = (i < n) ? counts[i] : 0;
    __syncthreads();
    for (int off = 1; off < 256; off <<= 1) {
        int x = (t >= off) ? s[t - off] : 0;
        __syncthreads();
        s[t] += x;
        __syncthreads();
    }
    if (i < n) row_ptr[i + 1] = s[t];
    if (t == 255) blockSums[blockIdx.x] = s[255];
}

__global__ __launch_bounds__(256) void k_scan2(const int* __restrict__ blockSums, int* __restrict__ blockOff, int nb) {
    __shared__ int s[256];
    int t = threadIdx.x;
    s[t] = (t < nb) ? blockSums[t] : 0;
    __syncthreads();
    for (int off = 1; off < 256; off <<= 1) {
        int x = (t >= off) ? s[t - off] : 0;
        __syncthreads();
        s[t] += x;
        __syncthreads();
    }
    blockOff[t] = (t == 0) ? 0 : s[t - 1];
}

__global__ __launch_bounds__(256) void k_scan3(int* __restrict__ row_ptr, const int* __restrict__ blockOff, int n) {
    int i = blockIdx.x * 256 + threadIdx.x;
    if (i < n) row_ptr[i + 1] += blockOff[blockIdx.x];
    if (blockIdx.x == 0 && threadIdx.x == 0) row_ptr[0] = 0;
}

__global__ __launch_bounds__(256) void k_scatter(const int* __restrict__ src, const int* __restrict__ dst,
                                                 const int* __restrict__ row_ptr, int* __restrict__ cursor,
                                                 int* __restrict__ ssrc, int E) {
    int e = blockIdx.x * 256 + threadIdx.x;
    if (e < E) {
        int d = dst[e];
        int pos = row_ptr[d] + atomicAdd(&cursor[d], 1);
        ssrc[pos] = src[e];
    }
}

// ---------------- node GEMM (layer 1 only): [P|Q] = act @ WcT^T, P gets +b1 ----------------
__global__ __launch_bounds__(256) void k_gemm1(const f16* __restrict__ act, const f16* __restrict__ WcT,
                                               const float* __restrict__ b1,
                                               f16* __restrict__ P, f16* __restrict__ Q, int nrows) {
    int t = threadIdx.x;
    int w = t >> 6, lane = t & 63;
    int m = lane & 15, q = lane >> 4;
    int row0 = blockIdx.x * 64 + w * 16;
    int rowc = min(row0 + m, nrows - 1);
    f16x8 a[4];
#pragma unroll
    for (int kk = 0; kk < 4; ++kk)
        a[kk] = *(const f16x8*)(act + rowc * CH + kk * 32 + q * 8);
#pragma unroll
    for (int nb = 0; nb < 16; ++nb) {
        f32x4 acc = {0.f, 0.f, 0.f, 0.f};
#pragma unroll
        for (int kk = 0; kk < 4; ++kk) {
            f16x8 b = *(const f16x8*)(WcT + (nb * 16 + m) * CH + kk * 32 + q * 8);
            acc = mfma16(a[kk], b, acc);
        }
        int col = nb * 16 + m;
        float bias = (nb < 8) ? b1[col] : 0.f;
#pragma unroll
        for (int r = 0; r < 4; ++r) {
            int ro = row0 + q * 4 + r;
            if (ro < nrows) {
                float v = acc[r] + bias;
                if (nb < 8) P[ro * CH + col] = (f16)v;
                else        Q[ro * CH + (col - CH)] = (f16)v;
            }
        }
    }
}

// ---------------- fused edge GEMM + segmented max (+ optional next-layer GEMM-1) ----------
// 4-wave cooperative, dst-sorted CSR, 16-edge tiles, descriptor-driven pipeline.
// flags: bit0 relu out, bit1 fp32 final out, bit2 fused epilogue: node outputs go to LDS
//        and [P|Q]_next = out @ WcTn^T (+b1n on P half) is written to Pout/Qout.
__global__ __launch_bounds__(256, 4) void k_edge(const f16* __restrict__ P, const f16* __restrict__ Q,
                                                 const f16* __restrict__ W2Tg, const float* __restrict__ b2,
                                                 const int* __restrict__ row_ptr, const int* __restrict__ ssrc,
                                                 f16* __restrict__ act_out, float* __restrict__ final_out,
                                                 const f16* __restrict__ WcTn, const float* __restrict__ b1n,
                                                 f16* __restrict__ Pout, f16* __restrict__ Qout,
                                                 int n_nodes, int flags) {
    __shared__ __align__(16) f16 buf[2][16 * 136];
    __shared__ __align__(16) f16 outbuf[16 * 136];   // fused-mode node outputs (row=node, stride 136)
    __shared__ int rp[NPB + 1];
    __shared__ int tnd[MAXT], te0[MAXT];
    __shared__ int ntd_s, more_s;

    int t = threadIdx.x;
    int w = t >> 6, lane = t & 63;
    int m1 = lane & 15, q1 = lane >> 4;   // consumer coords
    int mp = t >> 4, c = t & 15;          // producer coords: edge-in-tile, chunk
    int n0 = blockIdx.x * NPB;
    const f16x8 z8 = {};

    if (t <= NPB) rp[t] = row_ptr[min(n0 + t, n_nodes)];
    if (flags & 4) {   // zero-init outbuf (covers zero-degree nodes)
#pragma unroll
        for (int g = t; g < 16 * 136 / 8; g += 256) ((f16x8*)outbuf)[g] = z8;
    }

    // this wave's 2 nb-blocks of W2^T (32 VGPRs)
    f16x8 bf[2][4];
#pragma unroll
    for (int i2 = 0; i2 < 2; ++i2)
#pragma unroll
        for (int kk = 0; kk < 4; ++kk)
            bf[i2][kk] = *(const f16x8*)(W2Tg + ((2 * w + i2) * 16 + m1) * CH + kk * 32 + q1 * 8);
    float bias0 = b2[(2 * w) * 16 + m1];
    float bias1 = b2[(2 * w + 1) * 16 + m1];

    f32x4 mx[2];
    mx[0] = {-1e30f, -1e30f, -1e30f, -1e30f};
    mx[1] = {-1e30f, -1e30f, -1e30f, -1e30f};
    int cur_nd = -1;

    auto flush = [&](int nd) {
        if (nd >= 0) {
            int node = n0 + nd;
#pragma unroll
            for (int i2 = 0; i2 < 2; ++i2) {
                float v = fmaxf(fmaxf(mx[i2][0], mx[i2][1]), fmaxf(mx[i2][2], mx[i2][3]));
                v = fmaxf(v, __shfl_xor(v, 16));
                v = fmaxf(v, __shfl_xor(v, 32));
                if (q1 == 0) {
                    int col = (2 * w + i2) * 16 + m1;
                    float o = v + (i2 ? bias1 : bias0);
                    if (flags & 1) o = fmaxf(o, 0.f);
                    if (flags & 4)      outbuf[nd * 136 + col] = (f16)o;
                    else if (flags & 2) final_out[(size_t)node * CH + col] = o;
                    else                act_out[(size_t)node * CH + col] = (f16)o;
                }
                mx[i2] = {-1e30f, -1e30f, -1e30f, -1e30f};
            }
        }
    };

    int w_nd = 0, w_e = -2000000000;   // walker state (thread 0 only)

    for (;;) {
        __syncthreads();
        if (t == 0) {
            int k = 0;
            while (w_nd < NPB && k < MAXT) {
                int rs = rp[w_nd], re = rp[w_nd + 1];
                if (w_e < rs) w_e = rs;
                if (w_e < re) { tnd[k] = w_nd; te0[k] = w_e; ++k; w_e += 16; }
                else          { ++w_nd; w_e = -2000000000; }
            }
            ntd_s = k;
            more_s = (w_nd < NPB) ? 1 : 0;
        }
        __syncthreads();
        int ntd = ntd_s, more = more_s;

        if (ntd > 0) {
            f16x8 qD0, pD0, qD1, pD1;
            int s0 = 0, s1 = 0;
            // prologue: produce tile 0, load data for tile 1, s-idx for tile 2
            {
                int nd = tnd[0], e0 = te0[0], re = rp[nd + 1];
                int sA = ssrc[min(e0 + mp, re - 1)];
                f16x8 qa = *(const f16x8*)(Q + (size_t)sA * CH + c * 8);
                f16x8 pp = *(const f16x8*)(P + (size_t)(n0 + nd) * CH + c * 8);
                *(f16x8*)&buf[0][mp * 136 + c * 8] = __builtin_elementwise_max(pp + qa, z8);
            }
            if (ntd > 1) {
                int nd = tnd[1], e0 = te0[1], re = rp[nd + 1];
                int sA = ssrc[min(e0 + mp, re - 1)];
                qD1 = *(const f16x8*)(Q + (size_t)sA * CH + c * 8);
                pD1 = *(const f16x8*)(P + (size_t)(n0 + nd) * CH + c * 8);
            }
            if (ntd > 2) {
                int nd = tnd[2], e0 = te0[2], re = rp[nd + 1];
                s0 = ssrc[min(e0 + mp, re - 1)];
            }
            __syncthreads();

            auto step = [&](int i, int par,
                            f16x8& pq, f16x8& pP,     // data for tile i+1 (produce now)
                            f16x8& nq, f16x8& nP,     // fill: data for tile i+2
                            int sNow,                  // s-idx for tile i+2
                            int& sNext) {              // fill: s-idx for tile i+3
                if (i + 3 < ntd) {
                    int nd = tnd[i + 3], e0 = te0[i + 3], re = rp[nd + 1];
                    sNext = ssrc[min(e0 + mp, re - 1)];
                }
                if (i + 2 < ntd) {
                    int nd = tnd[i + 2];
                    nq = *(const f16x8*)(Q + (size_t)sNow * CH + c * 8);
                    nP = *(const f16x8*)(P + (size_t)(n0 + nd) * CH + c * 8);
                }
                int ndc = tnd[i];
                if (ndc != cur_nd) { flush(cur_nd); cur_nd = ndc; }
                {
                    const f16* bp = &buf[par][0];
                    f16x8 af[4];
#pragma unroll
                    for (int kk = 0; kk < 4; ++kk)
                        af[kk] = *(const f16x8*)&bp[m1 * 136 + kk * 32 + q1 * 8];
                    f32x4 a0 = {0.f, 0.f, 0.f, 0.f}, a1 = {0.f, 0.f, 0.f, 0.f};
#pragma unroll
                    for (int kk = 0; kk < 4; ++kk) {
                        a0 = mfma16(af[kk], bf[0][kk], a0);
                        a1 = mfma16(af[kk], bf[1][kk], a1);
                    }
                    mx[0] = __builtin_elementwise_max(mx[0], a0);
                    mx[1] = __builtin_elementwise_max(mx[1], a1);
                }
                if (i + 1 < ntd)
                    *(f16x8*)&buf[par ^ 1][mp * 136 + c * 8] = __builtin_elementwise_max(pP + pq, z8);
                __syncthreads();
            };

            int i = 0;
            while (i < ntd) {
                step(i, 0, qD1, pD1, qD0, pD0, s0, s1); ++i;
                if (i >= ntd) break;
                step(i, 1, qD0, pD0, qD1, pD1, s1, s0); ++i;
            }
        }
        if (!more) break;
    }
    flush(cur_nd);

    if (flags & 4) {
        // ---- fused next-layer GEMM-1: [P|Q]_next(16x256) = outbuf(16x128) @ WcTn^T ----
        __syncthreads();   // outbuf complete
        f16x8 af[4];
#pragma unroll
        for (int kk = 0; kk < 4; ++kk)
            af[kk] = *(const f16x8*)&outbuf[m1 * 136 + kk * 32 + q1 * 8];
#pragma unroll
        for (int i3 = 0; i3 < 4; ++i3) {
            int nb = 4 * w + i3;
            f32x4 acc = {0.f, 0.f, 0.f, 0.f};
#pragma unroll
            for (int kk = 0; kk < 4; ++kk) {
                f16x8 bb = *(const f16x8*)(WcTn + (nb * 16 + m1) * CH + kk * 32 + q1 * 8);
                acc = mfma16(af[kk], bb, acc);
            }
            int col = nb * 16 + m1;
            float bias = (nb < 8) ? b1n[col] : 0.f;
#pragma unroll
            for (int r = 0; r < 4; ++r) {
                int nd = q1 * 4 + r;
                int node = n0 + nd;
                if (node < n_nodes) {
                    float v = acc[r] + bias;
                    if (nb < 8) Pout[(size_t)node * CH + col] = (f16)v;
                    else        Qout[(size_t)node * CH + (col - CH)] = (f16)v;
                }
            }
        }
    } else {
        // zero-degree nodes (non-fused modes write global directly)
        for (int j = 0; j < NPB; ++j) {
            int node = n0 + j;
            if (node < n_nodes && rp[j + 1] == rp[j] && t < CH) {
                if (flags & 2) final_out[(size_t)node * CH + t] = 0.f;
                else           act_out[(size_t)node * CH + t] = (f16)0.f;
            }
        }
    }
}

extern "C" void kernel_launch(void* const* d_in, const int* in_sizes, int n_in,
                              void* d_out, int out_size, void* d_ws, size_t ws_size,
                              hipStream_t stream) {
    const float* x = (const float*)d_in[0];
    const int* ei  = (const int*)d_in[1];
    int E = in_sizes[1] / 2;
    int N = in_sizes[0] / CH;
    const int* esrc = ei;
    const int* edst = ei + E;

    const float* W1[3] = {(const float*)d_in[2], (const float*)d_in[6],  (const float*)d_in[10]};
    const float* B1[3] = {(const float*)d_in[3], (const float*)d_in[7],  (const float*)d_in[11]};
    const float* W2[3] = {(const float*)d_in[4], (const float*)d_in[8],  (const float*)d_in[12]};
    const float* B2[3] = {(const float*)d_in[5], (const float*)d_in[9],  (const float*)d_in[13]};

    char* base = (char*)d_ws;
    size_t off = 0;
    auto alloc = [&](size_t bytes) -> void* {
        void* p = base + off;
        off = (off + bytes + 255) & ~(size_t)255;
        return p;
    };
    int* counts    = (int*)alloc(sizeof(int) * (size_t)(N + 256));
    int* cursor    = (int*)alloc(sizeof(int) * (size_t)(N + 256));
    size_t zero_bytes = off;                       // counts + cursor must start at 0
    int* row_ptr   = (int*)alloc(sizeof(int) * (size_t)(N + 1));
    int* blockSums = (int*)alloc(sizeof(int) * 256);
    int* blockOff  = (int*)alloc(sizeof(int) * 256);
    int* ssrc      = (int*)alloc(sizeof(int) * (size_t)E);
    f16* act       = (f16*)alloc(sizeof(f16) * (size_t)N * CH);   // x in f16; recycled as P1
    f16* Pb        = (f16*)alloc(sizeof(f16) * (size_t)N * CH);
    f16* Qb        = (f16*)alloc(sizeof(f16) * (size_t)N * CH);
    f16* Qb2       = (f16*)alloc(sizeof(f16) * (size_t)N * CH);
    f16* WcT       = (f16*)alloc(sizeof(f16) * 3 * 256 * CH);
    f16* W2T       = (f16*)alloc(sizeof(f16) * 3 * CH * CH);

    hipMemsetAsync(d_ws, 0, zero_bytes, stream);

    int gE = (E + 255) / 256;
    int gN = (N + 255) / 256;
    int total4 = N * CH / 4;
    int gCvt = (total4 + 255) / 256;
    // fused: hist + 3x prep + cvt
    k_front<<<gE + 576 + gCvt, 256, 0, stream>>>(edst, counts, E,
                                                 W1[0], W2[0], W1[1], W2[1], W1[2], W2[2],
                                                 WcT, W2T, x, act, total4, gE);
    k_scan1<<<gN, 256, 0, stream>>>(counts, row_ptr, blockSums, N);
    k_scan2<<<1, 256, 0, stream>>>(blockSums, blockOff, gN);
    k_scan3<<<gN, 256, 0, stream>>>(row_ptr, blockOff, N);
    k_scatter<<<gE, 256, 0, stream>>>(esrc, edst, row_ptr, cursor, ssrc, E);

    // ping-pong P/Q sets: L1 reads (Pb,Qb) writes (act,Qb2); L2 reads (act,Qb2) writes (Pb,Qb); L3 reads (Pb,Qb)
    f16* P0 = Pb;  f16* Q0 = Qb;
    f16* P1 = act; f16* Q1 = Qb2;   // act's data is dead after k_gemm1

    int gEdge = (N + NPB - 1) / NPB;
    k_gemm1<<<(N + 63) / 64, 256, 0, stream>>>(act, WcT + 0 * 256 * CH, B1[0], P0, Q0, N);
    // layer 1: fused epilogue computes layer-2 [P|Q]
    k_edge<<<gEdge, 256, 0, stream>>>(P0, Q0, W2T + 0 * CH * CH, B2[0], row_ptr, ssrc,
                                      act, (float*)d_out,
                                      WcT + 1 * 256 * CH, B1[1], P1, Q1, N, 1 | 4);
    // layer 2: fused epilogue computes layer-3 [P|Q]
    k_edge<<<gEdge, 256, 0, stream>>>(P1, Q1, W2T + 1 * CH * CH, B2[1], row_ptr, ssrc,
                                      act, (float*)d_out,
                                      WcT + 2 * 256 * CH, B1[2], P0, Q0, N, 1 | 4);
    // layer 3: fp32 final output
    k_edge<<<gEdge, 256, 0, stream>>>(P0, Q0, W2T + 2 * CH * CH, B2[2], row_ptr, ssrc,
                                      act, (float*)d_out,
                                      WcT, B1[0], P1, Q1, N, 2);
}

// Round 7
// 460.877 us; speedup vs baseline: 1.9612x; 1.3075x over previous
//
#include <hip/hip_runtime.h>

#define CH 128
#define NPB 16    // nodes per block in k_edge

typedef _Float16 f16;
typedef _Float16 f16x8 __attribute__((ext_vector_type(8)));
typedef float f32x4 __attribute__((ext_vector_type(4)));

__device__ __forceinline__ f32x4 mfma16(f16x8 a, f16x8 b, f32x4 c) {
    return __builtin_amdgcn_mfma_f32_16x16x32_f16(a, b, c, 0, 0, 0);
}

// ---------------- fused front: hist + weight prep (3 layers) + x->f16 cvt ----------------
__global__ __launch_bounds__(256) void k_front(const int* __restrict__ edst, int* __restrict__ counts, int E,
                                               const float* __restrict__ W1a, const float* __restrict__ W2a,
                                               const float* __restrict__ W1b, const float* __restrict__ W2b,
                                               const float* __restrict__ W1c, const float* __restrict__ W2c,
                                               f16* __restrict__ WcT, f16* __restrict__ W2T,
                                               const float* __restrict__ x, f16* __restrict__ act,
                                               int total4, int gHist) {
    int bid = blockIdx.x;
    if (bid < gHist) {
        int e = bid * 256 + threadIdx.x;
        if (e < E) atomicAdd(&counts[edst[e]], 1);
    } else if (bid < gHist + 576) {
        int r = bid - gHist;
        int l = r / 192;
        const float* W1 = (l == 0) ? W1a : (l == 1) ? W1b : W1c;
        const float* W2 = (l == 0) ? W2a : (l == 1) ? W2b : W2c;
        f16* wct = WcT + l * 256 * CH;
        f16* w2t = W2T + l * CH * CH;
        int id = (r % 192) * 256 + threadIdx.x;   // 49152 per layer
        if (id < 32768) {
            int n = id >> 7, k = id & 127;
            float v;
            if (n < CH) v = W1[k * CH + n] - W1[(CH + k) * CH + n];
            else        v = W1[(CH + k) * CH + (n - CH)];
            wct[n * CH + k] = (f16)v;
        } else {
            int rr = id - 32768;
            int n = rr >> 7, k = rr & 127;
            w2t[n * CH + k] = (f16)W2[k * CH + n];
        }
    } else {
        int i = (bid - gHist - 576) * 256 + threadIdx.x;
        if (i < total4) {
            float4 v = ((const float4*)x)[i];
            f16 h0 = (f16)v.x, h1 = (f16)v.y, h2 = (f16)v.z, h3 = (f16)v.w;
            short4 s;
            s.x = *(short*)&h0; s.y = *(short*)&h1; s.z = *(short*)&h2; s.w = *(short*)&h3;
            ((short4*)act)[i] = s;
        }
    }
}

// ---------------- CSR scans + scatter ----------------
__global__ __launch_bounds__(256) void k_scan1(const int* __restrict__ counts, int* __restrict__ row_ptr,
                                               int* __restrict__ blockSums, int n) {
    __shared__ int s[256];
    int t = threadIdx.x;
    int i = blockIdx.x * 256 + t;
    s[t] = (i < n) ? counts[i] : 0;
    __syncthreads();
    for (int off = 1; off < 256; off <<= 1) {
        int x = (t >= off) ? s[t - off] : 0;
        __syncthreads();
        s[t] += x;
        __syncthreads();
    }
    if (i < n) row_ptr[i + 1] = s[t];
    if (t == 255) blockSums[blockIdx.x] = s[255];
}

__global__ __launch_bounds__(256) void k_scan2(const int* __restrict__ blockSums, int* __restrict__ blockOff, int nb) {
    __shared__ int s[256];
    int t = threadIdx.x;
    s[t] = (t < nb) ? blockSums[t] : 0;
    __syncthreads();
    for (int off = 1; off < 256; off <<= 1) {
        int x = (t >= off) ? s[t - off] : 0;
        __syncthreads();
        s[t] += x;
        __syncthreads();
    }
    blockOff[t] = (t == 0) ? 0 : s[t - 1];
}

__global__ __launch_bounds__(256) void k_scan3(int* __restrict__ row_ptr, const int* __restrict__ blockOff, int n) {
    int i = blockIdx.x * 256 + threadIdx.x;
    if (i < n) row_ptr[i + 1] += blockOff[blockIdx.x];
    if (blockIdx.x == 0 && threadIdx.x == 0) row_ptr[0] = 0;
}

__global__ __launch_bounds__(256) void k_scatter(const int* __restrict__ src, const int* __restrict__ dst,
                                                 const int* __restrict__ row_ptr, int* __restrict__ cursor,
                                                 int* __restrict__ ssrc, int* __restrict__ sdst, int E) {
    int e = blockIdx.x * 256 + threadIdx.x;
    if (e < E) {
        int d = dst[e];
        int pos = row_ptr[d] + atomicAdd(&cursor[d], 1);
        ssrc[pos] = src[e];
        sdst[pos] = d;
    }
}

// ---------------- node GEMM: [P|Q] = act @ WcT^T, P gets +b1. 256 rows/block ----------------
__global__ __launch_bounds__(256) void k_gemm1(const f16* __restrict__ act, const f16* __restrict__ WcT,
                                               const float* __restrict__ b1,
                                               f16* __restrict__ P, f16* __restrict__ Q, int nrows) {
    int t = threadIdx.x;
    int w = t >> 6, lane = t & 63;
    int m = lane & 15, q = lane >> 4;
    int rowbase = blockIdx.x * 256 + w * 64;
    f16x8 a[4][4];   // [row-tile][kk]
#pragma unroll
    for (int rt = 0; rt < 4; ++rt) {
        int rowc = min(rowbase + rt * 16 + m, nrows - 1);
#pragma unroll
        for (int kk = 0; kk < 4; ++kk)
            a[rt][kk] = *(const f16x8*)(act + (size_t)rowc * CH + kk * 32 + q * 8);
    }
#pragma unroll
    for (int nb = 0; nb < 16; ++nb) {
        f16x8 b[4];
#pragma unroll
        for (int kk = 0; kk < 4; ++kk)
            b[kk] = *(const f16x8*)(WcT + (nb * 16 + m) * CH + kk * 32 + q * 8);
        int col = nb * 16 + m;
        float bias = (nb < 8) ? b1[col] : 0.f;
#pragma unroll
        for (int rt = 0; rt < 4; ++rt) {
            f32x4 acc = {0.f, 0.f, 0.f, 0.f};
#pragma unroll
            for (int kk = 0; kk < 4; ++kk) acc = mfma16(a[rt][kk], b[kk], acc);
#pragma unroll
            for (int r = 0; r < 4; ++r) {
                int ro = rowbase + rt * 16 + q * 4 + r;
                if (ro < nrows) {
                    float v = acc[r] + bias;
                    if (nb < 8) P[(size_t)ro * CH + col] = (f16)v;
                    else        Q[(size_t)ro * CH + (col - CH)] = (f16)v;
                }
            }
        }
    }
}

// ---------------- fused edge GEMM + segmented max: PACKED 32-edge tiles ----------------
// Tiles stride straight through the block's dst-sorted edge range (zero padding).
// Per-block LDS max-accumulator (flipped-float u32, atomicMax); acc==0 <=> deg==0.
// flags: bit0 relu out, bit1 fp32 final out.
__global__ __launch_bounds__(256) void k_edge(const f16* __restrict__ P, const f16* __restrict__ Q,
                                              const f16* __restrict__ W2Tg, const float* __restrict__ b2,
                                              const int* __restrict__ row_ptr, const int* __restrict__ ssrc,
                                              const int* __restrict__ sdst,
                                              f16* __restrict__ act_out, float* __restrict__ final_out,
                                              int n_nodes, int flags) {
    __shared__ __align__(16) f16 buf[2][32 * 136];
    __shared__ unsigned char ndrel[2][32];
    __shared__ unsigned accs[NPB * CH];

    int t = threadIdx.x;
    int w = t >> 6, lane = t & 63;
    int m1 = lane & 15, q1 = lane >> 4;   // consumer coords
    int mp = t >> 4, c = t & 15;          // producer coords: slot, chunk
    int n0 = blockIdx.x * NPB;
    const f16x8 z8 = {};

#pragma unroll
    for (int i = t; i < NPB * CH; i += 256) accs[i] = 0u;

    int rs = row_ptr[min(n0, n_nodes)];
    int re = row_ptr[min(n0 + NPB, n_nodes)];
    int ntiles = (re - rs + 31) >> 5;

    // this wave's 2 nb-blocks of W2^T (32 VGPRs)
    f16x8 bf[2][4];
#pragma unroll
    for (int i2 = 0; i2 < 2; ++i2)
#pragma unroll
        for (int kk = 0; kk < 4; ++kk)
            bf[i2][kk] = *(const f16x8*)(W2Tg + ((2 * w + i2) * 16 + m1) * CH + kk * 32 + q1 * 8);

    auto consume = [&](int par) {
#pragma unroll
        for (int rt = 0; rt < 2; ++rt) {
            f16x8 af[4];
#pragma unroll
            for (int kk = 0; kk < 4; ++kk)
                af[kk] = *(const f16x8*)&buf[par][(rt * 16 + m1) * 136 + kk * 32 + q1 * 8];
            unsigned nid4 = *(const unsigned*)&ndrel[par][rt * 16 + q1 * 4];
#pragma unroll
            for (int i2 = 0; i2 < 2; ++i2) {
                f32x4 a = {0.f, 0.f, 0.f, 0.f};
#pragma unroll
                for (int kk = 0; kk < 4; ++kk) a = mfma16(af[kk], bf[i2][kk], a);
                int col = (2 * w + i2) * 16 + m1;
#pragma unroll
                for (int r = 0; r < 4; ++r) {
                    int node = (nid4 >> (8 * r)) & 255;
                    unsigned u = __float_as_uint(a[r]);
                    unsigned f = u ^ (0x80000000u | (unsigned)((int)u >> 31));
                    atomicMax(&accs[node * CH + col], f);
                }
            }
        }
    };

    if (ntiles > 0) {
        // pipeline regs: idx sets (s=src, d=dst) and data sets, 2 parities
        int sa0, da0, sb0, db0, sa1, da1, sb1, db1;
        f16x8 qa0, pa0, qb0, pb0, qa1, pa1, qb1, pb1;

        auto loadIdx = [&](int tt, int& sa, int& da, int& sb, int& db) {
            int e0 = rs + tt * 32;
            int ea = min(e0 + mp, re - 1), eb = min(e0 + 16 + mp, re - 1);
            sa = ssrc[ea]; da = sdst[ea];
            sb = ssrc[eb]; db = sdst[eb];
        };
        auto loadData = [&](int sa, int da, int sb, int db,
                            f16x8& qa, f16x8& pa, f16x8& qb, f16x8& pb) {
            qa = *(const f16x8*)(Q + (size_t)sa * CH + c * 8);
            pa = *(const f16x8*)(P + (size_t)da * CH + c * 8);
            qb = *(const f16x8*)(Q + (size_t)sb * CH + c * 8);
            pb = *(const f16x8*)(P + (size_t)db * CH + c * 8);
        };
        auto produce = [&](int par, f16x8 qa, f16x8 pa, f16x8 qb, f16x8 pb, int da, int db) {
            *(f16x8*)&buf[par][mp * 136 + c * 8]        = __builtin_elementwise_max(pa + qa, z8);
            *(f16x8*)&buf[par][(16 + mp) * 136 + c * 8] = __builtin_elementwise_max(pb + qb, z8);
            if (c == 0) {
                ndrel[par][mp]      = (unsigned char)(da - n0);
                ndrel[par][16 + mp] = (unsigned char)(db - n0);
            }
        };

        // prologue: tile0 -> buf0; data(1) -> set1; idx(2) -> set0
        loadIdx(0, sa0, da0, sb0, db0);
        loadData(sa0, da0, sb0, db0, qa0, pa0, qb0, pb0);
        produce(0, qa0, pa0, qb0, pb0, da0, db0);
        if (ntiles > 1) {
            loadIdx(1, sa1, da1, sb1, db1);
            loadData(sa1, da1, sb1, db1, qa1, pa1, qb1, pb1);
        }
        if (ntiles > 2) loadIdx(2, sa0, da0, sb0, db0);
        __syncthreads();

        auto step = [&](int i, int par,
                        f16x8& pqa, f16x8& ppa, f16x8& pqb, f16x8& ppb, int pda, int pdb, // data+dst for tile i+1
                        f16x8& nqa, f16x8& npa, f16x8& nqb, f16x8& npb,                   // fill: data tile i+2
                        int sa2, int da2, int sb2, int db2,                               // idx for tile i+2
                        int& sa3, int& da3, int& sb3, int& db3) {                          // fill: idx tile i+3
            if (i + 3 < ntiles) loadIdx(i + 3, sa3, da3, sb3, db3);
            if (i + 2 < ntiles) loadData(sa2, da2, sb2, db2, nqa, npa, nqb, npb);
            consume(par);
            if (i + 1 < ntiles) produce(par ^ 1, pqa, ppa, pqb, ppb, pda, pdb);
            __syncthreads();
        };

        int i = 0;
        while (i < ntiles) {
            step(i, 0, qa1, pa1, qb1, pb1, da1, db1, qa0, pa0, qb0, pb0,
                 sa0, da0, sb0, db0, sa1, da1, sb1, db1); ++i;
            if (i >= ntiles) break;
            step(i, 1, qa0, pa0, qb0, pb0, da0, db0, qa1, pa1, qb1, pb1,
                 sa1, da1, sb1, db1, sa0, da0, sb0, db0); ++i;
        }
    }
    __syncthreads();

    // writeback: unflip + bias (+relu), zero-degree -> 0
#pragma unroll
    for (int j = 0; j < NPB * CH / 256; ++j) {
        int idx = t + j * 256;
        int node = idx >> 7, col = idx & 127;
        int gn = n0 + node;
        if (gn < n_nodes) {
            unsigned u = accs[idx];
            float o = 0.f;
            if (u != 0u) {
                float v = (u & 0x80000000u) ? __uint_as_float(u & 0x7FFFFFFFu)
                                            : __uint_as_float(~u);
                o = v + b2[col];
                if (flags & 1) o = fmaxf(o, 0.f);
            }
            if (flags & 2) final_out[(size_t)gn * CH + col] = o;
            else           act_out[(size_t)gn * CH + col] = (f16)o;
        }
    }
}

extern "C" void kernel_launch(void* const* d_in, const int* in_sizes, int n_in,
                              void* d_out, int out_size, void* d_ws, size_t ws_size,
                              hipStream_t stream) {
    const float* x = (const float*)d_in[0];
    const int* ei  = (const int*)d_in[1];
    int E = in_sizes[1] / 2;
    int N = in_sizes[0] / CH;
    const int* esrc = ei;
    const int* edst = ei + E;

    const float* W1[3] = {(const float*)d_in[2], (const float*)d_in[6],  (const float*)d_in[10]};
    const float* B1[3] = {(const float*)d_in[3], (const float*)d_in[7],  (const float*)d_in[11]};
    const float* W2[3] = {(const float*)d_in[4], (const float*)d_in[8],  (const float*)d_in[12]};
    const float* B2[3] = {(const float*)d_in[5], (const float*)d_in[9],  (const float*)d_in[13]};

    char* base = (char*)d_ws;
    size_t off = 0;
    auto alloc = [&](size_t bytes) -> void* {
        void* p = base + off;
        off = (off + bytes + 255) & ~(size_t)255;
        return p;
    };
    int* counts    = (int*)alloc(sizeof(int) * (size_t)(N + 256));
    int* cursor    = (int*)alloc(sizeof(int) * (size_t)(N + 256));
    size_t zero_bytes = off;                       // counts + cursor must start at 0
    int* row_ptr   = (int*)alloc(sizeof(int) * (size_t)(N + 1));
    int* blockSums = (int*)alloc(sizeof(int) * 256);
    int* blockOff  = (int*)alloc(sizeof(int) * 256);
    int* ssrc      = (int*)alloc(sizeof(int) * (size_t)E);
    int* sdst      = (int*)alloc(sizeof(int) * (size_t)E);
    f16* act       = (f16*)alloc(sizeof(f16) * (size_t)N * CH);
    f16* Pb        = (f16*)alloc(sizeof(f16) * (size_t)N * CH);
    f16* Qb        = (f16*)alloc(sizeof(f16) * (size_t)N * CH);
    f16* WcT       = (f16*)alloc(sizeof(f16) * 3 * 256 * CH);
    f16* W2T       = (f16*)alloc(sizeof(f16) * 3 * CH * CH);

    hipMemsetAsync(d_ws, 0, zero_bytes, stream);

    int gE = (E + 255) / 256;
    int gN = (N + 255) / 256;
    int total4 = N * CH / 4;
    int gCvt = (total4 + 255) / 256;
    // fused: hist + 3x prep + cvt
    k_front<<<gE + 576 + gCvt, 256, 0, stream>>>(edst, counts, E,
                                                 W1[0], W2[0], W1[1], W2[1], W1[2], W2[2],
                                                 WcT, W2T, x, act, total4, gE);
    k_scan1<<<gN, 256, 0, stream>>>(counts, row_ptr, blockSums, N);
    k_scan2<<<1, 256, 0, stream>>>(blockSums, blockOff, gN);
    k_scan3<<<gN, 256, 0, stream>>>(row_ptr, blockOff, N);
    k_scatter<<<gE, 256, 0, stream>>>(esrc, edst, row_ptr, cursor, ssrc, sdst, E);

    int gEdge = (N + NPB - 1) / NPB;
    int gG1 = (N + 255) / 256;
    for (int l = 0; l < 3; ++l) {
        k_gemm1<<<gG1, 256, 0, stream>>>(act, WcT + l * 256 * CH, B1[l], Pb, Qb, N);
        int flags = (l < 2) ? 1 : 2;
        k_edge<<<gEdge, 256, 0, stream>>>(Pb, Qb, W2T + l * CH * CH, B2[l],
                                          row_ptr, ssrc, sdst, act, (float*)d_out, N, flags);
    }
}

// Round 8
// 435.682 us; speedup vs baseline: 2.0746x; 1.0578x over previous
//
#include <hip/hip_runtime.h>

#define CH 128
#define NPB 16    // nodes per block in k_edge

typedef _Float16 f16;
typedef _Float16 f16x8 __attribute__((ext_vector_type(8)));
typedef float f32x4 __attribute__((ext_vector_type(4)));

__device__ __forceinline__ f32x4 mfma16(f16x8 a, f16x8 b, f32x4 c) {
    return __builtin_amdgcn_mfma_f32_16x16x32_f16(a, b, c, 0, 0, 0);
}

// ---------------- fused front: hist + weight prep (3 layers) + x->f16 cvt ----------------
__global__ __launch_bounds__(256) void k_front(const int* __restrict__ edst, int* __restrict__ counts, int E,
                                               const float* __restrict__ W1a, const float* __restrict__ W2a,
                                               const float* __restrict__ W1b, const float* __restrict__ W2b,
                                               const float* __restrict__ W1c, const float* __restrict__ W2c,
                                               f16* __restrict__ WcT, f16* __restrict__ W2T,
                                               const float* __restrict__ x, f16* __restrict__ act,
                                               int total4, int gHist) {
    int bid = blockIdx.x;
    if (bid < gHist) {
        int e = bid * 256 + threadIdx.x;
        if (e < E) atomicAdd(&counts[edst[e]], 1);
    } else if (bid < gHist + 576) {
        int r = bid - gHist;
        int l = r / 192;
        const float* W1 = (l == 0) ? W1a : (l == 1) ? W1b : W1c;
        const float* W2 = (l == 0) ? W2a : (l == 1) ? W2b : W2c;
        f16* wct = WcT + l * 256 * CH;
        f16* w2t = W2T + l * CH * CH;
        int id = (r % 192) * 256 + threadIdx.x;   // 49152 per layer
        if (id < 32768) {
            int n = id >> 7, k = id & 127;
            float v;
            if (n < CH) v = W1[k * CH + n] - W1[(CH + k) * CH + n];
            else        v = W1[(CH + k) * CH + (n - CH)];
            wct[n * CH + k] = (f16)v;
        } else {
            int rr = id - 32768;
            int n = rr >> 7, k = rr & 127;
            w2t[n * CH + k] = (f16)W2[k * CH + n];
        }
    } else {
        int i = (bid - gHist - 576) * 256 + threadIdx.x;
        if (i < total4) {
            float4 v = ((const float4*)x)[i];
            f16 h0 = (f16)v.x, h1 = (f16)v.y, h2 = (f16)v.z, h3 = (f16)v.w;
            short4 s;
            s.x = *(short*)&h0; s.y = *(short*)&h1; s.z = *(short*)&h2; s.w = *(short*)&h3;
            ((short4*)act)[i] = s;
        }
    }
}

// ---------------- CSR scans + scatter ----------------
__global__ __launch_bounds__(256) void k_scan1(const int* __restrict__ counts, int* __restrict__ row_ptr,
                                               int* __restrict__ blockSums, int n) {
    __shared__ int s[256];
    int t = threadIdx.x;
    int i = blockIdx.x * 256 + t;
    s[t] = (i < n) ? counts[i] : 0;
    __syncthreads();
    for (int off = 1; off < 256; off <<= 1) {
        int x = (t >= off) ? s[t - off] : 0;
        __syncthreads();
        s[t] += x;
        __syncthreads();
    }
    if (i < n) row_ptr[i + 1] = s[t];
    if (t == 255) blockSums[blockIdx.x] = s[255];
}

__global__ __launch_bounds__(256) void k_scan2(const int* __restrict__ blockSums, int* __restrict__ blockOff, int nb) {
    __shared__ int s[256];
    int t = threadIdx.x;
    s[t] = (t < nb) ? blockSums[t] : 0;
    __syncthreads();
    for (int off = 1; off < 256; off <<= 1) {
        int x = (t >= off) ? s[t - off] : 0;
        __syncthreads();
        s[t] += x;
        __syncthreads();
    }
    blockOff[t] = (t == 0) ? 0 : s[t - 1];
}

__global__ __launch_bounds__(256) void k_scan3(int* __restrict__ row_ptr, const int* __restrict__ blockOff, int n) {
    int i = blockIdx.x * 256 + threadIdx.x;
    if (i < n) row_ptr[i + 1] += blockOff[blockIdx.x];
    if (blockIdx.x == 0 && threadIdx.x == 0) row_ptr[0] = 0;
}

// int2-packed scatter: one 8B store per edge (halves dirtied cache lines vs 2x4B)
__global__ __launch_bounds__(256) void k_scatter(const int* __restrict__ src, const int* __restrict__ dst,
                                                 const int* __restrict__ row_ptr, int* __restrict__ cursor,
                                                 int2* __restrict__ sed, int E) {
    int e = blockIdx.x * 256 + threadIdx.x;
    if (e < E) {
        int d = dst[e];
        int pos = row_ptr[d] + atomicAdd(&cursor[d], 1);
        sed[pos] = make_int2(src[e], d);
    }
}

// ---------------- node GEMM: [P|Q] = act @ WcT^T, P gets +b1. 256 rows/block ----------------
__global__ __launch_bounds__(256) void k_gemm1(const f16* __restrict__ act, const f16* __restrict__ WcT,
                                               const float* __restrict__ b1,
                                               f16* __restrict__ P, f16* __restrict__ Q, int nrows) {
    int t = threadIdx.x;
    int w = t >> 6, lane = t & 63;
    int m = lane & 15, q = lane >> 4;
    int rowbase = blockIdx.x * 256 + w * 64;
    f16x8 a[4][4];   // [row-tile][kk]
#pragma unroll
    for (int rt = 0; rt < 4; ++rt) {
        int rowc = min(rowbase + rt * 16 + m, nrows - 1);
#pragma unroll
        for (int kk = 0; kk < 4; ++kk)
            a[rt][kk] = *(const f16x8*)(act + (size_t)rowc * CH + kk * 32 + q * 8);
    }
#pragma unroll
    for (int nb = 0; nb < 16; ++nb) {
        f16x8 b[4];
#pragma unroll
        for (int kk = 0; kk < 4; ++kk)
            b[kk] = *(const f16x8*)(WcT + (nb * 16 + m) * CH + kk * 32 + q * 8);
        int col = nb * 16 + m;
        float bias = (nb < 8) ? b1[col] : 0.f;
#pragma unroll
        for (int rt = 0; rt < 4; ++rt) {
            f32x4 acc = {0.f, 0.f, 0.f, 0.f};
#pragma unroll
            for (int kk = 0; kk < 4; ++kk) acc = mfma16(a[rt][kk], b[kk], acc);
#pragma unroll
            for (int r = 0; r < 4; ++r) {
                int ro = rowbase + rt * 16 + q * 4 + r;
                if (ro < nrows) {
                    float v = acc[r] + bias;
                    if (nb < 8) P[(size_t)ro * CH + col] = (f16)v;
                    else        Q[(size_t)ro * CH + (col - CH)] = (f16)v;
                }
            }
        }
    }
}

// ---------------- fused edge GEMM + segmented max: PACKED 32-edge tiles ----------------
// Tiles stride straight through the block's dst-sorted edge range (zero padding).
// Per-block LDS max-accumulator (flipped-float u32, atomicMax); acc==0 <=> deg==0.
// Quad-uniform folding: if all 4 C-frag slots share a node (~75% of quads), 1 atomic not 4.
// flags: bit0 relu out, bit1 fp32 final out.
__global__ __launch_bounds__(256) void k_edge(const f16* __restrict__ P, const f16* __restrict__ Q,
                                              const f16* __restrict__ W2Tg, const float* __restrict__ b2,
                                              const int* __restrict__ row_ptr, const int2* __restrict__ sed,
                                              f16* __restrict__ act_out, float* __restrict__ final_out,
                                              int n_nodes, int flags) {
    __shared__ __align__(16) f16 buf[2][32 * 136];
    __shared__ unsigned char ndrel[2][32];
    __shared__ unsigned accs[NPB * CH];

    int t = threadIdx.x;
    int w = t >> 6, lane = t & 63;
    int m1 = lane & 15, q1 = lane >> 4;   // consumer coords
    int mp = t >> 4, c = t & 15;          // producer coords: slot, chunk
    int n0 = blockIdx.x * NPB;
    const f16x8 z8 = {};

#pragma unroll
    for (int i = t; i < NPB * CH; i += 256) accs[i] = 0u;

    int rs = row_ptr[min(n0, n_nodes)];
    int re = row_ptr[min(n0 + NPB, n_nodes)];
    int ntiles = (re - rs + 31) >> 5;

    // this wave's 2 nb-blocks of W2^T (32 VGPRs)
    f16x8 bf[2][4];
#pragma unroll
    for (int i2 = 0; i2 < 2; ++i2)
#pragma unroll
        for (int kk = 0; kk < 4; ++kk)
            bf[i2][kk] = *(const f16x8*)(W2Tg + ((2 * w + i2) * 16 + m1) * CH + kk * 32 + q1 * 8);

    auto flip = [](float x) -> unsigned {
        unsigned u = __float_as_uint(x);
        return u ^ (0x80000000u | (unsigned)((int)u >> 31));
    };

    auto consume = [&](int par) {
#pragma unroll
        for (int rt = 0; rt < 2; ++rt) {
            f16x8 af[4];
#pragma unroll
            for (int kk = 0; kk < 4; ++kk)
                af[kk] = *(const f16x8*)&buf[par][(rt * 16 + m1) * 136 + kk * 32 + q1 * 8];
            unsigned nid4 = *(const unsigned*)&ndrel[par][rt * 16 + q1 * 4];
            unsigned b0 = nid4 & 255u;
            bool uni = (nid4 == b0 * 0x01010101u);
#pragma unroll
            for (int i2 = 0; i2 < 2; ++i2) {
                f32x4 a = {0.f, 0.f, 0.f, 0.f};
#pragma unroll
                for (int kk = 0; kk < 4; ++kk) a = mfma16(af[kk], bf[i2][kk], a);
                int col = (2 * w + i2) * 16 + m1;
                if (uni) {
                    float m = fmaxf(fmaxf(a[0], a[1]), fmaxf(a[2], a[3]));
                    atomicMax(&accs[b0 * CH + col], flip(m));
                } else {
#pragma unroll
                    for (int r = 0; r < 4; ++r) {
                        int node = (nid4 >> (8 * r)) & 255;
                        atomicMax(&accs[node * CH + col], flip(a[r]));
                    }
                }
            }
        }
    };

    if (ntiles > 0) {
        // pipeline regs: idx sets (x=src, y=dst) and data sets, 2 parities
        int2 ia0, ib0, ia1, ib1;
        f16x8 qa0, pa0, qb0, pb0, qa1, pa1, qb1, pb1;

        auto loadIdx = [&](int tt, int2& ia, int2& ib) {
            int e0 = rs + tt * 32;
            ia = sed[min(e0 + mp, re - 1)];
            ib = sed[min(e0 + 16 + mp, re - 1)];
        };
        auto loadData = [&](int2 ia, int2 ib,
                            f16x8& qa, f16x8& pa, f16x8& qb, f16x8& pb) {
            qa = *(const f16x8*)(Q + (size_t)ia.x * CH + c * 8);
            pa = *(const f16x8*)(P + (size_t)ia.y * CH + c * 8);
            qb = *(const f16x8*)(Q + (size_t)ib.x * CH + c * 8);
            pb = *(const f16x8*)(P + (size_t)ib.y * CH + c * 8);
        };
        auto produce = [&](int par, f16x8 qa, f16x8 pa, f16x8 qb, f16x8 pb, int da, int db) {
            *(f16x8*)&buf[par][mp * 136 + c * 8]        = __builtin_elementwise_max(pa + qa, z8);
            *(f16x8*)&buf[par][(16 + mp) * 136 + c * 8] = __builtin_elementwise_max(pb + qb, z8);
            if (c == 0) {
                ndrel[par][mp]      = (unsigned char)(da - n0);
                ndrel[par][16 + mp] = (unsigned char)(db - n0);
            }
        };

        // prologue: tile0 -> buf0; data(1) -> set1; idx(2) -> set0
        loadIdx(0, ia0, ib0);
        loadData(ia0, ib0, qa0, pa0, qb0, pb0);
        produce(0, qa0, pa0, qb0, pb0, ia0.y, ib0.y);
        if (ntiles > 1) {
            loadIdx(1, ia1, ib1);
            loadData(ia1, ib1, qa1, pa1, qb1, pb1);
        }
        if (ntiles > 2) loadIdx(2, ia0, ib0);
        __syncthreads();

        auto step = [&](int i, int par,
                        f16x8& pqa, f16x8& ppa, f16x8& pqb, f16x8& ppb, int pda, int pdb, // data+dst for tile i+1
                        f16x8& nqa, f16x8& npa, f16x8& nqb, f16x8& npb,                   // fill: data tile i+2
                        int2 i2a, int2 i2b,                                               // idx for tile i+2
                        int2& i3a, int2& i3b) {                                            // fill: idx tile i+3
            if (i + 3 < ntiles) loadIdx(i + 3, i3a, i3b);
            if (i + 2 < ntiles) loadData(i2a, i2b, nqa, npa, nqb, npb);
            consume(par);
            if (i + 1 < ntiles) produce(par ^ 1, pqa, ppa, pqb, ppb, pda, pdb);
            __syncthreads();
        };

        int i = 0;
        while (i < ntiles) {
            step(i, 0, qa1, pa1, qb1, pb1, ia1.y, ib1.y, qa0, pa0, qb0, pb0,
                 ia0, ib0, ia1, ib1); ++i;
            if (i >= ntiles) break;
            step(i, 1, qa0, pa0, qb0, pb0, ia0.y, ib0.y, qa1, pa1, qb1, pb1,
                 ia1, ib1, ia0, ib0); ++i;
        }
    }
    __syncthreads();

    // writeback: unflip + bias (+relu), zero-degree -> 0
#pragma unroll
    for (int j = 0; j < NPB * CH / 256; ++j) {
        int idx = t + j * 256;
        int node = idx >> 7, col = idx & 127;
        int gn = n0 + node;
        if (gn < n_nodes) {
            unsigned u = accs[idx];
            float o = 0.f;
            if (u != 0u) {
                float v = (u & 0x80000000u) ? __uint_as_float(u & 0x7FFFFFFFu)
                                            : __uint_as_float(~u);
                o = v + b2[col];
                if (flags & 1) o = fmaxf(o, 0.f);
            }
            if (flags & 2) final_out[(size_t)gn * CH + col] = o;
            else           act_out[(size_t)gn * CH + col] = (f16)o;
        }
    }
}

extern "C" void kernel_launch(void* const* d_in, const int* in_sizes, int n_in,
                              void* d_out, int out_size, void* d_ws, size_t ws_size,
                              hipStream_t stream) {
    const float* x = (const float*)d_in[0];
    const int* ei  = (const int*)d_in[1];
    int E = in_sizes[1] / 2;
    int N = in_sizes[0] / CH;
    const int* esrc = ei;
    const int* edst = ei + E;

    const float* W1[3] = {(const float*)d_in[2], (const float*)d_in[6],  (const float*)d_in[10]};
    const float* B1[3] = {(const float*)d_in[3], (const float*)d_in[7],  (const float*)d_in[11]};
    const float* W2[3] = {(const float*)d_in[4], (const float*)d_in[8],  (const float*)d_in[12]};
    const float* B2[3] = {(const float*)d_in[5], (const float*)d_in[9],  (const float*)d_in[13]};

    char* base = (char*)d_ws;
    size_t off = 0;
    auto alloc = [&](size_t bytes) -> void* {
        void* p = base + off;
        off = (off + bytes + 255) & ~(size_t)255;
        return p;
    };
    int* counts    = (int*)alloc(sizeof(int) * (size_t)(N + 256));
    int* cursor    = (int*)alloc(sizeof(int) * (size_t)(N + 256));
    size_t zero_bytes = off;                       // counts + cursor must start at 0
    int* row_ptr   = (int*)alloc(sizeof(int) * (size_t)(N + 1));
    int* blockSums = (int*)alloc(sizeof(int) * 256);
    int* blockOff  = (int*)alloc(sizeof(int) * 256);
    int2* sed      = (int2*)alloc(sizeof(int2) * (size_t)E);
    f16* act       = (f16*)alloc(sizeof(f16) * (size_t)N * CH);
    f16* Pb        = (f16*)alloc(sizeof(f16) * (size_t)N * CH);
    f16* Qb        = (f16*)alloc(sizeof(f16) * (size_t)N * CH);
    f16* WcT       = (f16*)alloc(sizeof(f16) * 3 * 256 * CH);
    f16* W2T       = (f16*)alloc(sizeof(f16) * 3 * CH * CH);

    hipMemsetAsync(d_ws, 0, zero_bytes, stream);

    int gE = (E + 255) / 256;
    int gN = (N + 255) / 256;
    int total4 = N * CH / 4;
    int gCvt = (total4 + 255) / 256;
    // fused: hist + 3x prep + cvt
    k_front<<<gE + 576 + gCvt, 256, 0, stream>>>(edst, counts, E,
                                                 W1[0], W2[0], W1[1], W2[1], W1[2], W2[2],
                                                 WcT, W2T, x, act, total4, gE);
    k_scan1<<<gN, 256, 0, stream>>>(counts, row_ptr, blockSums, N);
    k_scan2<<<1, 256, 0, stream>>>(blockSums, blockOff, gN);
    k_scan3<<<gN, 256, 0, stream>>>(row_ptr, blockOff, N);
    k_scatter<<<gE, 256, 0, stream>>>(esrc, edst, row_ptr, cursor, sed, E);

    int gEdge = (N + NPB - 1) / NPB;
    int gG1 = (N + 255) / 256;
    for (int l = 0; l < 3; ++l) {
        k_gemm1<<<gG1, 256, 0, stream>>>(act, WcT + l * 256 * CH, B1[l], Pb, Qb, N);
        int flags = (l < 2) ? 1 : 2;
        k_edge<<<gEdge, 256, 0, stream>>>(Pb, Qb, W2T + l * CH * CH, B2[l],
                                          row_ptr, sed, act, (float*)d_out, N, flags);
    }
}